// Round 9
// baseline (223.200 us; speedup 1.0000x reference)
//
#include <hip/hip_runtime.h>
#include <stdint.h>

// Problem constants
#define B 8
#define N 2048
#define D 16
#define KNN 32
#define DM 256
#define CAP 256  // candidate cap; approx-tau yields ~44 candidates (z~30 margin)

// ---------------------------------------------------------------------------
// K1: fused prep (proven). xcrd stored TRANSPOSED [B][D][N] so knn_main's
// fill loads are lane-contiguous.  Block 64: W transpose + pe bias/loss.
// ---------------------------------------------------------------------------
__global__ __launch_bounds__(256) void knn_prep(
    const float* __restrict__ x, const float* __restrict__ features,
    const float* __restrict__ Wc, const float* __restrict__ Wf,
    const float* __restrict__ pec, const float* __restrict__ pef,
    float* __restrict__ xcrdT, float* __restrict__ sq,
    float* __restrict__ Tc, float* __restrict__ Tf,
    float* __restrict__ WcT, float* __restrict__ WfT,
    float* __restrict__ cbias, float* __restrict__ pe_loss_out)
{
    if (blockIdx.x == 64) {
        int dm = threadIdx.x;
        float cb = 0.f, al = 0.f;
#pragma unroll
        for (int p = 0; p < D; ++p)
            cb += pec[p * DM + dm] + pef[p * DM + dm];
#pragma unroll
        for (int p = 0; p < D; ++p)
            al += fabsf(pec[p * DM + dm]) + fabsf(pef[p * DM + dm]);
        cbias[dm] = cb;
#pragma unroll
        for (int k = 0; k < KNN; ++k) {
            WcT[k * DM + dm] = Wc[dm * KNN + k];
            WfT[k * DM + dm] = Wf[dm * KNN + k];
        }
        __shared__ float redf[256];
        redf[dm] = al; __syncthreads();
        for (int st = 128; st > 0; st >>= 1) {
            if (dm < st) redf[dm] += redf[dm + st];
            __syncthreads();
        }
        if (dm == 0) pe_loss_out[0] = redf[0];
        return;
    }

    int tid = threadIdx.x;
    int b = blockIdx.x >> 3;

    // ---- own-batch stats: 8 rows per thread, fp64 accumulate ----
    double ls[D], lq[D];
#pragma unroll
    for (int d = 0; d < D; ++d) { ls[d] = 0.0; lq[d] = 0.0; }
    for (int r = 0; r < 8; ++r) {
        const float* row = x + ((size_t)b * N + r * 256 + tid) * D;
#pragma unroll
        for (int d = 0; d < D; d += 4) {
            float4 v = *(const float4*)(row + d);
            double x0 = v.x, x1 = v.y, x2 = v.z, x3 = v.w;
            ls[d]   += x0; lq[d]   += x0 * x0;
            ls[d+1] += x1; lq[d+1] += x1 * x1;
            ls[d+2] += x2; lq[d+2] += x2 * x2;
            ls[d+3] += x3; lq[d+3] += x3 * x3;
        }
    }
#pragma unroll
    for (int d = 0; d < D; ++d) {
        double s = ls[d], q = lq[d];
#pragma unroll
        for (int st = 32; st >= 1; st >>= 1) {
            s += __shfl_xor(s, st, 64);
            q += __shfl_xor(q, st, 64);
        }
        ls[d] = s; lq[d] = q;
    }
    __shared__ double sred[4][2 * D];
    __shared__ float smean[32], sscale[32];
    int wave = tid >> 6, lane = tid & 63;
    if (lane == 0) {
#pragma unroll
        for (int d = 0; d < D; ++d) {
            sred[wave][d]     = ls[d];
            sred[wave][D + d] = lq[d];
        }
    }
    __syncthreads();
    if (tid < D) {
        int d = tid;
        double S = sred[0][d] + sred[1][d] + sred[2][d] + sred[3][d];
        double Q = sred[0][D+d] + sred[1][D+d] + sred[2][D+d] + sred[3][D+d];
        double mean = S / (double)N;
        double var  = (Q - S * S / (double)N) / (double)(N - 1);
        if (var < 0.0) var = 0.0;
        float stdv = (float)sqrt(var);
        float scl  = 1.0f / (stdv + 1e-5f);
        float scl0 = 1.0f / (0.0f + 1e-5f);
        bool mask = features[b * D + d] > 0.1f;
        smean [d]      = mask ? 0.0f : (float)mean;
        sscale[d]      = mask ? scl0 : scl;
        smean [16 + d] = mask ? (float)mean : 0.0f;
        sscale[16 + d] = mask ? scl : scl0;
    }
    __syncthreads();

    // ---- per-point processing (identical arithmetic; transposed store) ----
    int t = blockIdx.x * 256 + tid;
    int nn = t & (N - 1);
    float tc = 0.f, tf = 0.f, s = 0.f;
    float row[D];
#pragma unroll
    for (int d = 0; d < D; ++d) {
        float xv = x[(size_t)t * D + d];
        bool mask = features[b * D + d] > 0.1f;
        float xc = mask ? 0.f : xv;
        float xf = mask ? xv : 0.f;
        row[d] = xc;
        s += xc * xc;                            // sequential, mirrors ref sq
        float vc = (xc - smean[d])      * sscale[d];
        vc = fminf(10.f, fmaxf(-10.f, vc));
        float vf = (xf - smean[16 + d]) * sscale[16 + d];
        vf = fminf(10.f, fmaxf(-10.f, vf));
        tc += vc; tf += vf;
    }
#pragma unroll
    for (int d = 0; d < D; ++d)                  // coalesced per-d across wave
        xcrdT[((size_t)b * D + d) * N + nn] = row[d];
    sq[t] = s; Tc[t] = tc; Tf[t] = tf;
}

// ---------------------------------------------------------------------------
// K2: ROUND-9 -- FOUR consecutive queries per wave (round 7/8 proven
// amortization doubled).  Every fill load feeds 4 dot accumulators, every
// matvec W load feeds 4 outputs: per-query fill loads 256->128, waves
// halve.  Fill keeps the round-8 proven 2-deep named-buffer pipeline.
// orig[4][32] is expected to be AGPR-parked (round-8 evidence: 2q kernel
// reported VGPR=60 < live orig state -> unified-file parking).
// Per-query selection unchanged (bit-identical): fused lane-min during
// fill -> tau = 32nd-smallest of 64 lane-minima (superset bound) ->
// ballot-compact -> 4-way-interleaved in-wave 64-key u64 bitonic rank
// (T<=64 fast path; exact serial fallback).
// Spill tripwire: WRITE_SIZE must stay 16384 KB (pure output).
// ---------------------------------------------------------------------------
#define LOADBUF(buf, sqm, j) do {                                   \
    int m_ = (j) * 64 + lane;                                       \
    _Pragma("unroll")                                               \
    for (int d_ = 0; d_ < D; ++d_)                                  \
        buf[d_] = xbT[(size_t)d_ * N + m_];                         \
    sqm = sqb[m_];                                                  \
} while (0)

#define COMPUTE4(j, buf, sqm) do {                                  \
    float a0_ = 0.f, a1_ = 0.f, a2_ = 0.f, a3_ = 0.f;               \
    _Pragma("unroll")                                               \
    for (int d_ = 0; d_ < D; ++d_) {                                \
        float v_ = buf[d_];                                         \
        a0_ += qx0[d_] * v_;                                        \
        a1_ += qx1[d_] * v_;                                        \
        a2_ += qx2[d_] * v_;                                        \
        a3_ += qx3[d_] * v_;                                        \
    }                                                               \
    orig0[j] = fabsf(sqrtf(fmaxf(sqn0 + sqm - 2.0f * a0_, 0.f)));   \
    orig1[j] = fabsf(sqrtf(fmaxf(sqn1 + sqm - 2.0f * a1_, 0.f)));   \
    orig2[j] = fabsf(sqrtf(fmaxf(sqn2 + sqm - 2.0f * a2_, 0.f)));   \
    orig3[j] = fabsf(sqrtf(fmaxf(sqn3 + sqm - 2.0f * a3_, 0.f)));   \
    vm0 = fminf(vm0, orig0[j]); vm1 = fminf(vm1, orig1[j]);         \
    vm2 = fminf(vm2, orig2[j]); vm3 = fminf(vm3, orig3[j]);         \
} while (0)

#define COMPACT(origX, tauX, cidx, TX) do {                         \
    int base_ = 0;                                                  \
    _Pragma("unroll")                                               \
    for (int j_ = 0; j_ < KNN; ++j_) {                              \
        bool f_ = (origX[j_] <= tauX);                              \
        unsigned long long mk_ = __ballot(f_);                      \
        if (f_) {                                                   \
            int pos_ = base_ + (int)__popcll(mk_ & lmask);          \
            if (pos_ < CAP)                                         \
                collect[cidx][pos_] =                               \
                    (((unsigned long long)__float_as_uint(origX[j_])) << 11) \
                    | (unsigned)(j_ * 64 + lane);                   \
        }                                                           \
        base_ += (int)__popcll(mk_);                                \
    }                                                               \
    TX = base_ < CAP ? base_ : CAP;                                 \
} while (0)

__global__ __launch_bounds__(64, 2) void knn_main(
    const float* __restrict__ xcrdT, const float* __restrict__ sq,
    const float* __restrict__ Tc, const float* __restrict__ Tf,
    const float* __restrict__ WcT, const float* __restrict__ WfT,
    const float* __restrict__ cbias, float* __restrict__ out)
{
    __shared__ unsigned long long collect[4][CAP];
    __shared__ int sortedm[4][KNN];
    __shared__ float akbk[4][KNN][2];            // [query][k][{a,b}]

    const int lane = threadIdx.x;
    const int qid0 = blockIdx.x * 4;             // multiple of 4
    const int b  = qid0 >> 11;
    const int n0 = qid0 & (N - 1);               // multiple of 4
    const int n1 = n0 + 1, n2 = n0 + 2, n3 = n0 + 3;

    const float* xbT = xcrdT + (size_t)b * D * N;
    const float* sqb = sq + b * N;

    // four query rows (n0..n3 adjacent -> float4 loads)
    float qx0[D], qx1[D], qx2[D], qx3[D];
#pragma unroll
    for (int d = 0; d < D; ++d) {
        float4 v = *(const float4*)(xbT + (size_t)d * N + n0);
        qx0[d] = v.x; qx1[d] = v.y; qx2[d] = v.z; qx3[d] = v.w;
    }
    const float sqn0 = sqb[n0], sqn1 = sqb[n1];
    const float sqn2 = sqb[n2], sqn3 = sqb[n3];

    // ---- fill: 2-deep register-double-buffered, shared by 4 queries ----
    float orig0[KNN], orig1[KNN], orig2[KNN], orig3[KNN];
    float vm0 = 1e30f, vm1 = 1e30f, vm2 = 1e30f, vm3 = 1e30f;
    {
        float buf0[D], buf1[D];
        float sqm0v, sqm1v;
        LOADBUF(buf0, sqm0v, 0);
#pragma unroll
        for (int jj = 0; jj < KNN; jj += 2) {
            LOADBUF(buf1, sqm1v, jj + 1);
            COMPUTE4(jj, buf0, sqm0v);
            if (jj + 2 < KNN) LOADBUF(buf0, sqm0v, jj + 2);
            COMPUTE4(jj + 1, buf1, sqm1v);
        }
    }

    // ---- approx tau per query: 32nd-smallest of the 64 per-lane minima ----
#pragma unroll
    for (int k = 2; k <= 64; k <<= 1) {
#pragma unroll
        for (int j = k >> 1; j >= 1; j >>= 1) {
            float o0 = __shfl_xor(vm0, j, 64);
            float o1 = __shfl_xor(vm1, j, 64);
            float o2 = __shfl_xor(vm2, j, 64);
            float o3 = __shfl_xor(vm3, j, 64);
            bool lower = (lane & j) == 0;
            bool up    = (lane & k) == 0;
            vm0 = (lower == up) ? fminf(vm0, o0) : fmaxf(vm0, o0);
            vm1 = (lower == up) ? fminf(vm1, o1) : fmaxf(vm1, o1);
            vm2 = (lower == up) ? fminf(vm2, o2) : fmaxf(vm2, o2);
            vm3 = (lower == up) ? fminf(vm3, o3) : fmaxf(vm3, o3);
        }
    }
    const float tau0 = __shfl(vm0, 31, 64);
    const float tau1 = __shfl(vm1, 31, 64);
    const float tau2 = __shfl(vm2, 31, 64);
    const float tau3 = __shfl(vm3, 31, 64);

    // ---- tie-fixup compact, per query ----
    const unsigned long long lmask = (1ULL << lane) - 1ULL;
    int T0, T1, T2, T3;
    COMPACT(orig0, tau0, 0, T0);
    COMPACT(orig1, tau1, 1, T1);
    COMPACT(orig2, tau2, 2, T2);
    COMPACT(orig3, tau3, 3, T3);
    __syncthreads();

    if (T0 <= 64 && T1 <= 64 && T2 <= 64 && T3 <= 64) {
        // ---- fast path: four interleaved in-wave 64-key bitonic sorts ----
        unsigned long long key0 = (lane < T0) ? collect[0][lane] : ~0ULL;
        unsigned long long key1 = (lane < T1) ? collect[1][lane] : ~0ULL;
        unsigned long long key2 = (lane < T2) ? collect[2][lane] : ~0ULL;
        unsigned long long key3 = (lane < T3) ? collect[3][lane] : ~0ULL;
#pragma unroll
        for (int k = 2; k <= 64; k <<= 1) {
#pragma unroll
            for (int j = k >> 1; j >= 1; j >>= 1) {
                unsigned long long o0 = __shfl_xor(key0, j, 64);
                unsigned long long o1 = __shfl_xor(key1, j, 64);
                unsigned long long o2 = __shfl_xor(key2, j, 64);
                unsigned long long o3 = __shfl_xor(key3, j, 64);
                bool lower = (lane & j) == 0;
                bool up    = (lane & k) == 0;
                bool sel   = (lower == up);
                unsigned long long mn0 = (o0 < key0) ? o0 : key0;
                unsigned long long mx0 = (o0 < key0) ? key0 : o0;
                key0 = sel ? mn0 : mx0;
                unsigned long long mn1 = (o1 < key1) ? o1 : key1;
                unsigned long long mx1 = (o1 < key1) ? key1 : o1;
                key1 = sel ? mn1 : mx1;
                unsigned long long mn2 = (o2 < key2) ? o2 : key2;
                unsigned long long mx2 = (o2 < key2) ? key2 : o2;
                key2 = sel ? mn2 : mx2;
                unsigned long long mn3 = (o3 < key3) ? o3 : key3;
                unsigned long long mx3 = (o3 < key3) ? key3 : o3;
                key3 = sel ? mn3 : mx3;
            }
        }
        if (lane < KNN) {
            sortedm[0][lane] = (int)(key0 & 2047u);
            sortedm[1][lane] = (int)(key1 & 2047u);
            sortedm[2][lane] = (int)(key2 & 2047u);
            sortedm[3][lane] = (int)(key3 & 2047u);
        }
    } else {
        // ---- rare path: per-query fast/slow handling ----
#pragma unroll 1
        for (int q = 0; q < 4; ++q) {
            int T = (q == 0) ? T0 : (q == 1) ? T1 : (q == 2) ? T2 : T3;
            unsigned long long* co = collect[q];
            int* so = sortedm[q];
            if (T <= 64) {
                unsigned long long key = (lane < T) ? co[lane] : ~0ULL;
#pragma unroll
                for (int k = 2; k <= 64; k <<= 1) {
#pragma unroll
                    for (int j = k >> 1; j >= 1; j >>= 1) {
                        unsigned long long o = __shfl_xor(key, j, 64);
                        bool lower = (lane & j) == 0;
                        bool up    = (lane & k) == 0;
                        unsigned long long mn = (o < key) ? o : key;
                        unsigned long long mx = (o < key) ? key : o;
                        key = (lower == up) ? mn : mx;
                    }
                }
                if (lane < KNN) so[lane] = (int)(key & 2047u);
            } else {
#pragma unroll 1
                for (int slot = 0; slot < CAP / 64; ++slot) {
                    int i = lane + slot * 64;
                    if (i < T) {
                        unsigned long long mk = co[i];
                        int rank = 0;
#pragma unroll 4
                        for (int t2 = 0; t2 < T; ++t2)
                            rank += (co[t2] < mk) ? 1 : 0;
                        if (rank < KNN) so[rank] = (int)(mk & 2047u);
                    }
                }
            }
        }
    }
    __syncthreads();

    // ---- gather ak/bk lane-parallel: lane covers (q,k), two passes ----
    const float* Tcb = Tc + b * N;
    const float* Tfb = Tf + b * N;
    {
        const float Tcn0 = Tcb[n0], Tfn0 = Tfb[n0];
        const float Tcn1 = Tcb[n1], Tfn1 = Tfb[n1];
        const float Tcn2 = Tcb[n2], Tfn2 = Tfb[n2];
        const float Tcn3 = Tcb[n3], Tfn3 = Tfb[n3];
        int k  = lane & 31;
        int qh = lane >> 5;                      // 0 or 1
        int wmA = sortedm[qh][k];
        float TcnA = qh ? Tcn1 : Tcn0;
        float TfnA = qh ? Tfn1 : Tfn0;
        akbk[qh][k][0] = Tcb[wmA] - TcnA;
        akbk[qh][k][1] = Tfb[wmA] - TfnA;
        int wmB = sortedm[2 + qh][k];
        float TcnB = qh ? Tcn3 : Tcn2;
        float TfnB = qh ? Tfn3 : Tfn2;
        akbk[2 + qh][k][0] = Tcb[wmB] - TcnB;
        akbk[2 + qh][k][1] = Tfb[wmB] - TfnB;
    }
    __syncthreads();

    // ---- matvec: W loads shared by 4 queries; ak/bk from LDS bcast ----
    float acc0[4] = {0.f, 0.f, 0.f, 0.f};
    float acc1[4] = {0.f, 0.f, 0.f, 0.f};
    float acc2[4] = {0.f, 0.f, 0.f, 0.f};
    float acc3[4] = {0.f, 0.f, 0.f, 0.f};

#pragma unroll
    for (int k = 0; k < KNN; ++k) {
        float ak0 = akbk[0][k][0], bk0 = akbk[0][k][1];
        float ak1 = akbk[1][k][0], bk1 = akbk[1][k][1];
        float ak2 = akbk[2][k][0], bk2 = akbk[2][k][1];
        float ak3 = akbk[3][k][0], bk3 = akbk[3][k][1];
        const float* wc = WcT + k * DM + lane;
        const float* wf = WfT + k * DM + lane;
#pragma unroll
        for (int q = 0; q < 4; ++q) {
            float wcv = wc[q * 64];
            float wfv = wf[q * 64];
            acc0[q] += wcv * ak0 + wfv * bk0;
            acc1[q] += wcv * ak1 + wfv * bk1;
            acc2[q] += wcv * ak2 + wfv * bk2;
            acc3[q] += wcv * ak3 + wfv * bk3;
        }
    }

    size_t ob0 = (size_t)qid0 * DM + lane;
#pragma unroll
    for (int q = 0; q < 4; ++q) {
        float cb = cbias[lane + q * 64];
        out[ob0 + q * 64]          = acc0[q] + cb;
        out[ob0 + DM + q * 64]     = acc1[q] + cb;
        out[ob0 + 2 * DM + q * 64] = acc2[q] + cb;
        out[ob0 + 3 * DM + q * 64] = acc3[q] + cb;
    }
}

// ---------------------------------------------------------------------------
extern "C" void kernel_launch(void* const* d_in, const int* in_sizes, int n_in,
                              void* d_out, int out_size, void* d_ws, size_t ws_size,
                              hipStream_t stream)
{
    const float* x        = (const float*)d_in[0];   // (B,N,D)
    const float* features = (const float*)d_in[1];   // (B,D)
    const float* W_crd    = (const float*)d_in[2];   // (DM,K)
    const float* W_ftr    = (const float*)d_in[3];   // (DM,K)
    const float* pe_crd   = (const float*)d_in[4];   // (1,1,D,DM)
    const float* pe_ftr   = (const float*)d_in[5];   // (1,1,D,DM)
    // d_in[6] = k (constant 32), ignored

    float* out = (float*)d_out;                      // B*N*DM floats + 1 (pe_loss)

    float* xcrdT = (float*)d_ws;                     // 262144 (B*D*N, transposed)
    float* sqv   = xcrdT + (size_t)B * N * D;        // 16384
    float* Tc    = sqv  + B * N;                     // 16384
    float* Tf    = Tc   + B * N;                     // 16384
    float* cbias = Tf   + B * N;                     // 256
    float* WcT   = cbias + DM;                       // 8192
    float* WfT   = WcT + KNN * DM;                   // 8192

    knn_prep<<<65, 256, 0, stream>>>(x, features, W_crd, W_ftr, pe_crd, pe_ftr,
                                     xcrdT, sqv, Tc, Tf, WcT, WfT, cbias,
                                     out + (size_t)out_size - 1);
    knn_main<<<(B * N) / 4, 64, 0, stream>>>(xcrdT, sqv, Tc, Tf,
                                             WcT, WfT, cbias, out);
}

// Round 10
// 165.104 us; speedup vs baseline: 1.3519x; 1.3519x over previous
//
#include <hip/hip_runtime.h>
#include <stdint.h>

// Problem constants
#define B 8
#define N 2048
#define D 16
#define KNN 32
#define DM 256
#define CAP 128  // candidate cap; approx-tau yields ~44 +/- 7 candidates (z~13)

// ---------------------------------------------------------------------------
// K1: fused prep (proven). xcrd stored TRANSPOSED [B][D][N] so knn_main's
// staging loads are lane-contiguous.  Block 64: W transpose + pe bias/loss.
// ---------------------------------------------------------------------------
__global__ __launch_bounds__(256) void knn_prep(
    const float* __restrict__ x, const float* __restrict__ features,
    const float* __restrict__ Wc, const float* __restrict__ Wf,
    const float* __restrict__ pec, const float* __restrict__ pef,
    float* __restrict__ xcrdT, float* __restrict__ sq,
    float* __restrict__ Tc, float* __restrict__ Tf,
    float* __restrict__ WcT, float* __restrict__ WfT,
    float* __restrict__ cbias, float* __restrict__ pe_loss_out)
{
    if (blockIdx.x == 64) {
        int dm = threadIdx.x;
        float cb = 0.f, al = 0.f;
#pragma unroll
        for (int p = 0; p < D; ++p)
            cb += pec[p * DM + dm] + pef[p * DM + dm];
#pragma unroll
        for (int p = 0; p < D; ++p)
            al += fabsf(pec[p * DM + dm]) + fabsf(pef[p * DM + dm]);
        cbias[dm] = cb;
#pragma unroll
        for (int k = 0; k < KNN; ++k) {
            WcT[k * DM + dm] = Wc[dm * KNN + k];
            WfT[k * DM + dm] = Wf[dm * KNN + k];
        }
        __shared__ float redf[256];
        redf[dm] = al; __syncthreads();
        for (int st = 128; st > 0; st >>= 1) {
            if (dm < st) redf[dm] += redf[dm + st];
            __syncthreads();
        }
        if (dm == 0) pe_loss_out[0] = redf[0];
        return;
    }

    int tid = threadIdx.x;
    int b = blockIdx.x >> 3;

    // ---- own-batch stats: 8 rows per thread, fp64 accumulate ----
    double ls[D], lq[D];
#pragma unroll
    for (int d = 0; d < D; ++d) { ls[d] = 0.0; lq[d] = 0.0; }
    for (int r = 0; r < 8; ++r) {
        const float* row = x + ((size_t)b * N + r * 256 + tid) * D;
#pragma unroll
        for (int d = 0; d < D; d += 4) {
            float4 v = *(const float4*)(row + d);
            double x0 = v.x, x1 = v.y, x2 = v.z, x3 = v.w;
            ls[d]   += x0; lq[d]   += x0 * x0;
            ls[d+1] += x1; lq[d+1] += x1 * x1;
            ls[d+2] += x2; lq[d+2] += x2 * x2;
            ls[d+3] += x3; lq[d+3] += x3 * x3;
        }
    }
#pragma unroll
    for (int d = 0; d < D; ++d) {
        double s = ls[d], q = lq[d];
#pragma unroll
        for (int st = 32; st >= 1; st >>= 1) {
            s += __shfl_xor(s, st, 64);
            q += __shfl_xor(q, st, 64);
        }
        ls[d] = s; lq[d] = q;
    }
    __shared__ double sred[4][2 * D];
    __shared__ float smean[32], sscale[32];
    int wave = tid >> 6, lane = tid & 63;
    if (lane == 0) {
#pragma unroll
        for (int d = 0; d < D; ++d) {
            sred[wave][d]     = ls[d];
            sred[wave][D + d] = lq[d];
        }
    }
    __syncthreads();
    if (tid < D) {
        int d = tid;
        double S = sred[0][d] + sred[1][d] + sred[2][d] + sred[3][d];
        double Q = sred[0][D+d] + sred[1][D+d] + sred[2][D+d] + sred[3][D+d];
        double mean = S / (double)N;
        double var  = (Q - S * S / (double)N) / (double)(N - 1);
        if (var < 0.0) var = 0.0;
        float stdv = (float)sqrt(var);
        float scl  = 1.0f / (stdv + 1e-5f);
        float scl0 = 1.0f / (0.0f + 1e-5f);
        bool mask = features[b * D + d] > 0.1f;
        smean [d]      = mask ? 0.0f : (float)mean;
        sscale[d]      = mask ? scl0 : scl;
        smean [16 + d] = mask ? (float)mean : 0.0f;
        sscale[16 + d] = mask ? scl : scl0;
    }
    __syncthreads();

    // ---- per-point processing (identical arithmetic; transposed store) ----
    int t = blockIdx.x * 256 + tid;
    int nn = t & (N - 1);
    float tc = 0.f, tf = 0.f, s = 0.f;
    float row[D];
#pragma unroll
    for (int d = 0; d < D; ++d) {
        float xv = x[(size_t)t * D + d];
        bool mask = features[b * D + d] > 0.1f;
        float xc = mask ? 0.f : xv;
        float xf = mask ? xv : 0.f;
        row[d] = xc;
        s += xc * xc;                            // sequential, mirrors ref sq
        float vc = (xc - smean[d])      * sscale[d];
        vc = fminf(10.f, fmaxf(-10.f, vc));
        float vf = (xf - smean[16 + d]) * sscale[16 + d];
        vf = fminf(10.f, fmaxf(-10.f, vf));
        tc += vc; tf += vf;
    }
#pragma unroll
    for (int d = 0; d < D; ++d)                  // coalesced per-d across wave
        xcrdT[((size_t)b * D + d) * N + nn] = row[d];
    sq[t] = s; Tc[t] = tc; Tf[t] = tf;
}

// ---------------------------------------------------------------------------
// K2: ROUND-10 -- LDS panel staging.  Block = 4 waves = 8 consecutive
// queries (same batch: 8 | N).  The 128 KB batch panel is staged in eight
// 16 KB tiles [16 d][256 n] cooperatively (wave wid stages d = wid*4+dd,
// lane-contiguous dwordx4); each wave then runs the ROUND-8 PROVEN
// 2-queries-per-wave pipeline reading neighbors from LDS (544 L2-latency
// loads/wave -> 32 staging dwordx4 + 32 sq dwords + 544 cheap ds_reads).
// Partition m = j*64+lane with j = t*4+jt identical to round 8 ->
// distances, keys, and output are bit-identical.
// ds_read pattern tile[d][jt*64+lane]: stride 4B -> 2 lanes/bank (free).
// Selection phases are per-wave (shuffles + wave-private LDS slices with
// the r1-r3-proven lgkmcnt fence; no block barriers after the fill).
// LDS 27.6 KB/block -> ~5 blocks/CU = 20 waves/CU (2x round 8).
// Spill tripwire: WRITE_SIZE must stay 16384 KB.
// ---------------------------------------------------------------------------
#define WAVE_LDS_FENCE() do {                                   \
    asm volatile("s_waitcnt lgkmcnt(0)" ::: "memory");          \
    __builtin_amdgcn_sched_barrier(0);                          \
} while (0)

__global__ __launch_bounds__(256) void knn_main(
    const float* __restrict__ xcrdT, const float* __restrict__ sq,
    const float* __restrict__ Tc, const float* __restrict__ Tf,
    const float* __restrict__ WcT, const float* __restrict__ WfT,
    const float* __restrict__ cbias, float* __restrict__ out)
{
    __shared__ float tile[D][256];               // 16 KB panel tile
    __shared__ unsigned long long collect[8][CAP];
    __shared__ int sortedm[8][KNN];
    __shared__ float akbk[8][KNN][2];            // [q-slot][k][{a,b}]

    const int tid  = threadIdx.x;
    const int lane = tid & 63;
    const int wid  = tid >> 6;
    const int qid0 = blockIdx.x * 8 + wid * 2;   // even
    const int b  = qid0 >> 11;
    const int n0 = qid0 & (N - 1);
    const int n1 = n0 + 1;
    const int c0 = wid * 2, c1 = c0 + 1;         // this wave's LDS slots

    const float* xbT = xcrdT + (size_t)b * D * N;
    const float* sqb = sq + b * N;

    // two query rows (adjacent -> float2)
    float qx0[D], qx1[D];
#pragma unroll
    for (int d = 0; d < D; ++d) {
        float2 v = *(const float2*)(xbT + (size_t)d * N + n0);
        qx0[d] = v.x; qx1[d] = v.y;
    }
    const float sqn0 = sqb[n0], sqn1 = sqb[n1];

    // ---- fill: 8 staged tiles, round-8 arithmetic from LDS ----
    float orig0[KNN], orig1[KNN];
    float vm0 = 1e30f, vm1 = 1e30f;
#pragma unroll
    for (int t = 0; t < 8; ++t) {
        __syncthreads();                         // previous tile fully consumed
        {
            const float* src = xbT + (size_t)(wid * 4) * N + t * 256 + lane * 4;
#pragma unroll
            for (int dd = 0; dd < 4; ++dd) {
                float4 v = *(const float4*)(src + (size_t)dd * N);
                *(float4*)&tile[wid * 4 + dd][lane * 4] = v;
            }
        }
        __syncthreads();                         // tile ready for all waves
#pragma unroll
        for (int jt = 0; jt < 4; ++jt) {
            const int j  = t * 4 + jt;           // same j as round 8
            const int ml = jt * 64 + lane;       // m = j*64+lane (identical)
            float dot0 = 0.f, dot1 = 0.f;
#pragma unroll
            for (int d = 0; d < D; ++d) {
                float v = tile[d][ml];
                dot0 += qx0[d] * v;
                dot1 += qx1[d] * v;
            }
            float sm = sqb[t * 256 + ml];
            float o0 = fabsf(sqrtf(fmaxf(sqn0 + sm - 2.0f * dot0, 0.f)));
            float o1 = fabsf(sqrtf(fmaxf(sqn1 + sm - 2.0f * dot1, 0.f)));
            orig0[j] = o0; orig1[j] = o1;
            vm0 = fminf(vm0, o0); vm1 = fminf(vm1, o1);
        }
    }

    // ---- approx tau per query: 32nd-smallest of the 64 per-lane minima ----
#pragma unroll
    for (int k = 2; k <= 64; k <<= 1) {
#pragma unroll
        for (int j = k >> 1; j >= 1; j >>= 1) {
            float o0 = __shfl_xor(vm0, j, 64);
            float o1 = __shfl_xor(vm1, j, 64);
            bool lower = (lane & j) == 0;
            bool up    = (lane & k) == 0;
            vm0 = (lower == up) ? fminf(vm0, o0) : fmaxf(vm0, o0);
            vm1 = (lower == up) ? fminf(vm1, o1) : fmaxf(vm1, o1);
        }
    }
    const float tau0 = __shfl(vm0, 31, 64);      // >= exact 32nd smallest (q0)
    const float tau1 = __shfl(vm1, 31, 64);      // >= exact 32nd smallest (q1)

    // ---- tie-fixup compact, per query (wave-private LDS slice) ----
    const unsigned long long lmask = (1ULL << lane) - 1ULL;
    int T0, T1;
    {
        int base = 0;
#pragma unroll
        for (int j = 0; j < KNN; ++j) {
            bool f = (orig0[j] <= tau0);
            unsigned long long mk = __ballot(f);
            if (f) {
                int pos = base + (int)__popcll(mk & lmask);
                if (pos < CAP)
                    collect[c0][pos] =
                        (((unsigned long long)__float_as_uint(orig0[j])) << 11)
                        | (unsigned)(j * 64 + lane);
            }
            base += (int)__popcll(mk);
        }
        T0 = base < CAP ? base : CAP;
    }
    {
        int base = 0;
#pragma unroll
        for (int j = 0; j < KNN; ++j) {
            bool f = (orig1[j] <= tau1);
            unsigned long long mk = __ballot(f);
            if (f) {
                int pos = base + (int)__popcll(mk & lmask);
                if (pos < CAP)
                    collect[c1][pos] =
                        (((unsigned long long)__float_as_uint(orig1[j])) << 11)
                        | (unsigned)(j * 64 + lane);
            }
            base += (int)__popcll(mk);
        }
        T1 = base < CAP ? base : CAP;
    }
    WAVE_LDS_FENCE();                            // own-wave ds_writes drained

    if (T0 <= 64 && T1 <= 64) {
        // ---- fast path: two interleaved in-wave 64-key bitonic sorts ----
        unsigned long long key0 = (lane < T0) ? collect[c0][lane] : ~0ULL;
        unsigned long long key1 = (lane < T1) ? collect[c1][lane] : ~0ULL;
#pragma unroll
        for (int k = 2; k <= 64; k <<= 1) {
#pragma unroll
            for (int j = k >> 1; j >= 1; j >>= 1) {
                unsigned long long o0 = __shfl_xor(key0, j, 64);
                unsigned long long o1 = __shfl_xor(key1, j, 64);
                bool lower = (lane & j) == 0;
                bool up    = (lane & k) == 0;
                unsigned long long mn0 = (o0 < key0) ? o0 : key0;
                unsigned long long mx0 = (o0 < key0) ? key0 : o0;
                unsigned long long mn1 = (o1 < key1) ? o1 : key1;
                unsigned long long mx1 = (o1 < key1) ? key1 : o1;
                key0 = (lower == up) ? mn0 : mx0;
                key1 = (lower == up) ? mn1 : mx1;
            }
        }
        if (lane < KNN) {
            sortedm[c0][lane] = (int)(key0 & 2047u);
            sortedm[c1][lane] = (int)(key1 & 2047u);
        }
    } else {
        // ---- rare path: per-query fast/slow handling ----
#pragma unroll 1
        for (int q = 0; q < 2; ++q) {
            int T = q ? T1 : T0;
            unsigned long long* co = collect[q ? c1 : c0];
            int* so = sortedm[q ? c1 : c0];
            if (T <= 64) {
                unsigned long long key = (lane < T) ? co[lane] : ~0ULL;
#pragma unroll
                for (int k = 2; k <= 64; k <<= 1) {
#pragma unroll
                    for (int j = k >> 1; j >= 1; j >>= 1) {
                        unsigned long long o = __shfl_xor(key, j, 64);
                        bool lower = (lane & j) == 0;
                        bool up    = (lane & k) == 0;
                        unsigned long long mn = (o < key) ? o : key;
                        unsigned long long mx = (o < key) ? key : o;
                        key = (lower == up) ? mn : mx;
                    }
                }
                if (lane < KNN) so[lane] = (int)(key & 2047u);
            } else {
#pragma unroll 1
                for (int slot = 0; slot < CAP / 64; ++slot) {
                    int i = lane + slot * 64;
                    if (i < T) {
                        unsigned long long mk = co[i];
                        int rank = 0;
#pragma unroll 4
                        for (int t2 = 0; t2 < T; ++t2)
                            rank += (co[t2] < mk) ? 1 : 0;
                        if (rank < KNN) so[rank] = (int)(mk & 2047u);
                    }
                }
            }
        }
    }
    WAVE_LDS_FENCE();                            // sortedm visible to own wave

    // ---- gather ak/bk lane-parallel: lane = (q,k) ----
    const float* Tcb = Tc + b * N;
    const float* Tfb = Tf + b * N;
    {
        const float Tcn0 = Tcb[n0], Tfn0 = Tfb[n0];
        const float Tcn1 = Tcb[n1], Tfn1 = Tfb[n1];
        int q = lane >> 5;                       // 0 or 1
        int k = lane & 31;
        int wm = sortedm[c0 + q][k];
        float av = Tcb[wm] - (q ? Tcn1 : Tcn0);
        float bv = Tfb[wm] - (q ? Tfn1 : Tfn0);
        akbk[c0 + q][k][0] = av;
        akbk[c0 + q][k][1] = bv;
    }
    WAVE_LDS_FENCE();                            // akbk visible to own wave

    // ---- matvec: W loads shared by both queries; ak/bk from LDS bcast ----
    float acc0[4] = {0.f, 0.f, 0.f, 0.f};
    float acc1[4] = {0.f, 0.f, 0.f, 0.f};

#pragma unroll
    for (int k = 0; k < KNN; ++k) {
        float ak0 = akbk[c0][k][0], bk0 = akbk[c0][k][1];
        float ak1 = akbk[c1][k][0], bk1 = akbk[c1][k][1];
        const float* wc = WcT + k * DM + lane;
        const float* wf = WfT + k * DM + lane;
#pragma unroll
        for (int q = 0; q < 4; ++q) {
            float wcv = wc[q * 64];
            float wfv = wf[q * 64];
            acc0[q] += wcv * ak0 + wfv * bk0;
            acc1[q] += wcv * ak1 + wfv * bk1;
        }
    }

    size_t ob0 = (size_t)qid0 * DM + lane;
#pragma unroll
    for (int q = 0; q < 4; ++q) {
        float cb = cbias[lane + q * 64];
        out[ob0 + q * 64]      = acc0[q] + cb;
        out[ob0 + DM + q * 64] = acc1[q] + cb;
    }
}

// ---------------------------------------------------------------------------
extern "C" void kernel_launch(void* const* d_in, const int* in_sizes, int n_in,
                              void* d_out, int out_size, void* d_ws, size_t ws_size,
                              hipStream_t stream)
{
    const float* x        = (const float*)d_in[0];   // (B,N,D)
    const float* features = (const float*)d_in[1];   // (B,D)
    const float* W_crd    = (const float*)d_in[2];   // (DM,K)
    const float* W_ftr    = (const float*)d_in[3];   // (DM,K)
    const float* pe_crd   = (const float*)d_in[4];   // (1,1,D,DM)
    const float* pe_ftr   = (const float*)d_in[5];   // (1,1,D,DM)
    // d_in[6] = k (constant 32), ignored

    float* out = (float*)d_out;                      // B*N*DM floats + 1 (pe_loss)

    float* xcrdT = (float*)d_ws;                     // 262144 (B*D*N, transposed)
    float* sqv   = xcrdT + (size_t)B * N * D;        // 16384
    float* Tc    = sqv  + B * N;                     // 16384
    float* Tf    = Tc   + B * N;                     // 16384
    float* cbias = Tf   + B * N;                     // 256
    float* WcT   = cbias + DM;                       // 8192
    float* WfT   = WcT + KNN * DM;                   // 8192

    knn_prep<<<65, 256, 0, stream>>>(x, features, W_crd, W_ftr, pe_crd, pe_ftr,
                                     xcrdT, sqv, Tc, Tf, WcT, WfT, cbias,
                                     out + (size_t)out_size - 1);
    knn_main<<<(B * N) / 8, 256, 0, stream>>>(xcrdT, sqv, Tc, Tf,
                                              WcT, WfT, cbias, out);
}